// Round 2
// baseline (854.534 us; speedup 1.0000x reference)
//
#include <hip/hip_runtime.h>

// Problem constants (fixed by setup_inputs)
#define BB 8
#define CC 64
#define HH 128
#define WW 512
#define SS 512
#define HALF 256
#define HWP (HH * WW)        // 65536
#define BHW (BB * HWP)       // 524288
#define CELLS (BB * SS * SS) // 2097152
#define NSHARD 8             // one keys shard per XCD

__device__ __forceinline__ unsigned int order_f32(float f) {
    unsigned int u = __float_as_uint(f);
    return (u & 0x80000000u) ? ~u : (u | 0x80000000u);
}

// Kernel 1 (fused): per-block = 256 consecutive pixels of one batch.
//  (a) project each pixel, atomicMin packed (y, ~idx) key into the
//      XCD-private shard keys8[XCC_ID] with WORKGROUP scope -> the RMW
//      executes at this XCD's own L2 (no device-fabric round trip).
//      Sharding by the hardware XCC_ID register keeps this correct
//      regardless of dispatch->XCD mapping; the scatter merges shards.
//  (b) transpose this block's 256 pixels x 64 ch into img_t (B,HW,C).
//      The BW-bound transpose stream overlaps the latency-bound atomics.
__global__ __launch_bounds__(256) void proj_kernel(
    const float* __restrict__ img,
    const float* __restrict__ camera_k,
    const float* __restrict__ depth,
    const float* __restrict__ mpp_p,
    unsigned long long* __restrict__ keys8,
    float* __restrict__ img_t)
{
    __shared__ float sk[9];
    __shared__ float tile[64][65];

    const int gp0 = blockIdx.x * 256;   // first global pixel (incl. batch)
    const int b   = gp0 >> 16;          // HW = 65536
    const int t   = threadIdx.x;
    const int idx = gp0 + t;

    if (t == 0) {
        const float rs[3] = {0.5f, 0.5f, 1.0f};
        double a[9];
        #pragma unroll
        for (int i = 0; i < 3; ++i)
            #pragma unroll
            for (int j = 0; j < 3; ++j)
                a[i*3 + j] = (double)__fmul_rn(camera_k[b*9 + i*3 + j], rs[i]);
        double det = a[0]*(a[4]*a[8]-a[5]*a[7])
                   - a[1]*(a[3]*a[8]-a[5]*a[6])
                   + a[2]*(a[3]*a[7]-a[4]*a[6]);
        double inv[9];
        inv[0] =  (a[4]*a[8]-a[5]*a[7])/det;
        inv[1] = -(a[1]*a[8]-a[2]*a[7])/det;
        inv[2] =  (a[1]*a[5]-a[2]*a[4])/det;
        inv[3] = -(a[3]*a[8]-a[5]*a[6])/det;
        inv[4] =  (a[0]*a[8]-a[2]*a[6])/det;
        inv[5] = -(a[0]*a[5]-a[2]*a[3])/det;
        inv[6] =  (a[3]*a[7]-a[4]*a[6])/det;
        inv[7] = -(a[0]*a[7]-a[1]*a[6])/det;
        inv[8] =  (a[0]*a[4]-a[1]*a[3])/det;
        #pragma unroll
        for (int i = 0; i < 9; ++i) sk[i] = (float)inv[i];
    }
    __syncthreads();

    // ---- (a) projection + XCD-local atomic ----
    {
        const int rem = idx & (HWP - 1);
        const int v = rem >> 9;          // W = 512
        const int u = rem & (WW - 1);
        const float d = depth[idx];
        const float mpp = mpp_p[0];
        const float uf = (float)u, vf = (float)v;

        // Match numpy f32 semantics exactly: no FMA contraction.
        float xw = __fadd_rn(__fadd_rn(__fmul_rn(sk[0], uf), __fmul_rn(sk[1], vf)), sk[2]);
        float yw = __fadd_rn(__fadd_rn(__fmul_rn(sk[3], uf), __fmul_rn(sk[4], vf)), sk[5]);
        float zw = __fadd_rn(__fadd_rn(__fmul_rn(sk[6], uf), __fmul_rn(sk[7], vf)), sk[8]);
        float x3 = __fmul_rn(__fmul_rn(xw, d), 1.2f);
        float y3 = __fmul_rn(__fmul_rn(yw, d), 1.2f);
        float z3 = __fmul_rn(__fmul_rn(zw, d), 1.2f);

        int xi = (int)truncf(__fdiv_rn(x3, mpp));
        int zi = (int)truncf(__fdiv_rn(z3, mpp));

        if (xi >= -HALF && xi <= HALF - 1 && zi >= -HALF && zi <= HALF - 1) {
            int cell = (b << 18) | ((xi + HALF) << 9) | (zi + HALF);
            unsigned long long key =
                ((unsigned long long)order_f32(y3) << 32) | (unsigned int)(~idx);
            unsigned int xcc;
            asm volatile("s_getreg_b32 %0, hwreg(HW_REG_XCC_ID)" : "=s"(xcc));
            unsigned long long* shard = keys8 + (size_t)(xcc & (NSHARD - 1)) * CELLS;
            __hip_atomic_fetch_min(&shard[cell], key,
                                   __ATOMIC_RELAXED, __HIP_MEMORY_SCOPE_WORKGROUP);
        }
    }

    // ---- (b) transpose 256 px x 64 ch, in 4 sub-tiles of 64 px ----
    const int lane = t & 63;
    const int grp  = t >> 6;             // 0..3
    const int p0   = gp0 & (HWP - 1);
    const float* src = img + (size_t)b * CC * HWP + p0;
    float*       dst = img_t + (size_t)gp0 * CC;

    #pragma unroll
    for (int s4 = 0; s4 < 4; ++s4) {
        __syncthreads();
        const float* ssrc = src + s4 * 64;
        #pragma unroll
        for (int i = 0; i < 16; ++i) {
            int ch = grp * 16 + i;
            tile[lane][ch] = ssrc[(size_t)ch * HWP + lane];
        }
        __syncthreads();
        float* sdst = dst + (size_t)(s4 * 64) * CC;
        #pragma unroll
        for (int i = 0; i < 16; ++i) {
            int p = grp * 16 + i;
            sdst[(size_t)p * CC + lane] = tile[p][lane];
        }
    }
}

// Kernel 2: scatter. Block = 128 consecutive cells.
// Phase 0: merge the 8 XCD shards (coalesced) -> winner pixel per cell.
// Phase 1: per cell, one wave reads all 64 channels as ONE contiguous
//          256 B load from img_t into an XOR-swizzled LDS tile.
// Phase 2: channel-major fully-coalesced writes.
__global__ __launch_bounds__(256) void scatter_kernel(
    const float* __restrict__ img_t,
    const unsigned long long* __restrict__ keys8,
    float* __restrict__ out)
{
    __shared__ float sT[128 * 64];
    __shared__ int   sRem[128];

    const int cell0 = blockIdx.x * 128;
    const int b     = cell0 >> 18;
    const int t     = threadIdx.x;
    const int w     = t >> 6;     // wave 0..3
    const int l     = t & 63;     // lane

    if (t < 128) {
        const unsigned long long* kp = keys8 + cell0 + t;
        unsigned long long k = ~0ull;
        #pragma unroll
        for (int s = 0; s < NSHARD; ++s) {
            unsigned long long ks = kp[(size_t)s * CELLS];
            k = ks < k ? ks : k;
        }
        sRem[t] = (k == ~0ull) ? -1
                : (int)((~(unsigned int)(k & 0xFFFFFFFFull)) & (HWP - 1));
    }
    __syncthreads();

    const size_t bHWP = (size_t)b * HWP;
    #pragma unroll 8
    for (int i = 0; i < 32; ++i) {
        int cell = w * 32 + i;
        int r = sRem[cell];               // wave-uniform broadcast
        float val = 0.0f;
        if (r >= 0)                       // uniform branch
            val = img_t[((bHWP + (size_t)r) << 6) + l];
        sT[(cell << 6) + (l ^ (cell & 31))] = val;
    }
    __syncthreads();

    const int local = cell0 & (SS * SS - 1);
    float* op = out + (size_t)b * CC * (SS * SS) + local;
    #pragma unroll
    for (int j = 0; j < 16; ++j) {
        int c = w * 16 + j;
        float v0 = sT[((l)      << 6) + (c ^ (l & 31))];
        float v1 = sT[((l + 64) << 6) + (c ^ (l & 31))];
        float* oc = op + (size_t)c * (SS * SS);
        oc[l]      = v0;                  // 256 B coalesced per wave
        oc[64 + l] = v1;
    }
}

extern "C" void kernel_launch(void* const* d_in, const int* in_sizes, int n_in,
                              void* d_out, int out_size, void* d_ws, size_t ws_size,
                              hipStream_t stream) {
    const float* img      = (const float*)d_in[0];
    const float* camera_k = (const float*)d_in[1];
    const float* depth    = (const float*)d_in[2];
    const float* mpp      = (const float*)d_in[3];

    // ws layout: [0,128MiB) = 8 key shards, [128MiB,256MiB) = img_t
    unsigned long long* keys8 = (unsigned long long*)d_ws;
    float* img_t = (float*)((char*)d_ws + ((size_t)128 << 20));

    // Empty-cell sentinel = 0xFFFF.. (no finite y maps to it).
    hipMemsetAsync(keys8, 0xFF, (size_t)NSHARD * CELLS * sizeof(unsigned long long), stream);

    proj_kernel<<<BHW / 256, 256, 0, stream>>>(img, camera_k, depth, mpp, keys8, img_t);
    scatter_kernel<<<CELLS / 128, 256, 0, stream>>>(img_t, keys8, (float*)d_out);
}

// Round 3
// 837.251 us; speedup vs baseline: 1.0206x; 1.0206x over previous
//
#include <hip/hip_runtime.h>

// Problem constants (fixed by setup_inputs)
#define BB 8
#define CC 64
#define HH 128
#define WW 512
#define SS 512
#define HALF 256
#define HWP (HH * WW)        // 65536
#define BHW (BB * HWP)       // 524288
#define CELLS (BB * SS * SS) // 2097152

__device__ __forceinline__ unsigned int order_f32(float f) {
    unsigned int u = __float_as_uint(f);
    return (u & 0x80000000u) ? ~u : (u | 0x80000000u);
}

// Kernel 1: project pixels, atomicMin packed (y, ~idx) key per cell.
// (exact round-0 form: single shard, device-scope atomics)
__global__ __launch_bounds__(256) void proj_kernel(
    const float* __restrict__ camera_k,
    const float* __restrict__ depth,
    const float* __restrict__ mpp_p,
    unsigned long long* __restrict__ keys)
{
    __shared__ float sk[9];
    const int idx = blockIdx.x * 256 + threadIdx.x;   // all 256 pixels share one batch b
    const int b = idx >> 16;                          // HW = 65536

    if (threadIdx.x == 0) {
        const float rs[3] = {0.5f, 0.5f, 1.0f};
        double a[9];
        #pragma unroll
        for (int i = 0; i < 3; ++i)
            #pragma unroll
            for (int j = 0; j < 3; ++j)
                a[i*3 + j] = (double)__fmul_rn(camera_k[b*9 + i*3 + j], rs[i]);
        double det = a[0]*(a[4]*a[8]-a[5]*a[7])
                   - a[1]*(a[3]*a[8]-a[5]*a[6])
                   + a[2]*(a[3]*a[7]-a[4]*a[6]);
        double inv[9];
        inv[0] =  (a[4]*a[8]-a[5]*a[7])/det;
        inv[1] = -(a[1]*a[8]-a[2]*a[7])/det;
        inv[2] =  (a[1]*a[5]-a[2]*a[4])/det;
        inv[3] = -(a[3]*a[8]-a[5]*a[6])/det;
        inv[4] =  (a[0]*a[8]-a[2]*a[6])/det;
        inv[5] = -(a[0]*a[5]-a[2]*a[3])/det;
        inv[6] =  (a[3]*a[7]-a[4]*a[6])/det;
        inv[7] = -(a[0]*a[7]-a[1]*a[6])/det;
        inv[8] =  (a[0]*a[4]-a[1]*a[3])/det;
        #pragma unroll
        for (int i = 0; i < 9; ++i) sk[i] = (float)inv[i];
    }
    __syncthreads();

    const int rem = idx & (HWP - 1);
    const int v = rem >> 9;          // W = 512
    const int u = rem & (WW - 1);
    const float d = depth[idx];
    const float mpp = mpp_p[0];
    const float uf = (float)u, vf = (float)v;

    // Match numpy f32 semantics exactly: no FMA contraction on this chain.
    float xw = __fadd_rn(__fadd_rn(__fmul_rn(sk[0], uf), __fmul_rn(sk[1], vf)), sk[2]);
    float yw = __fadd_rn(__fadd_rn(__fmul_rn(sk[3], uf), __fmul_rn(sk[4], vf)), sk[5]);
    float zw = __fadd_rn(__fadd_rn(__fmul_rn(sk[6], uf), __fmul_rn(sk[7], vf)), sk[8]);
    float x3 = __fmul_rn(__fmul_rn(xw, d), 1.2f);
    float y3 = __fmul_rn(__fmul_rn(yw, d), 1.2f);
    float z3 = __fmul_rn(__fmul_rn(zw, d), 1.2f);

    int xi = (int)truncf(__fdiv_rn(x3, mpp));
    int zi = (int)truncf(__fdiv_rn(z3, mpp));

    if (xi >= -HALF && xi <= HALF - 1 && zi >= -HALF && zi <= HALF - 1) {
        int cell = (b << 18) | ((xi + HALF) << 9) | (zi + HALF);
        unsigned long long key =
            ((unsigned long long)order_f32(y3) << 32) | (unsigned int)(~idx);
        atomicMin(&keys[cell], key);
    }
}

// Kernel 2: scatter, single pass, NO transposed image.
// Block = 128 consecutive cells. Lanes = channels:
//  Phase 0: load the block's 128 keys once.
//  Phase 1: per cell, lane l gathers img[b][l][rem] (64 strided 4 B reads).
//           img (134 MB) fits L3; each 64 B line is reused ~10x by other
//           cells, so amplified line traffic is L3-served while HBM sees
//           ~134 MB once. All 32 loads per wave are hoisted -> deep MLP.
//           Stored to LDS with XOR swizzle (2-way, free).
//  Phase 2: channel-major writes, 256 B/wave-instr, NON-TEMPORAL so the
//           536 MB write stream does not evict img from L3.
__global__ __launch_bounds__(256) void scatter_kernel(
    const float* __restrict__ img,
    const unsigned long long* __restrict__ keys,
    float* __restrict__ out)
{
    __shared__ float sT[128 * 64];
    __shared__ int   sRem[128];

    const int cell0 = blockIdx.x * 128;
    const int b     = cell0 >> 18;
    const int t     = threadIdx.x;
    const int w     = t >> 6;     // wave 0..3
    const int l     = t & 63;     // lane = channel
    const int ci0   = w * 32;     // this wave's first cell-in-tile

    if (t < 128) {
        unsigned long long k = keys[cell0 + t];
        sRem[t] = (k == ~0ull) ? -1
                : (int)((~(unsigned int)(k & 0xFFFFFFFFull)) & (HWP - 1));
    }
    __syncthreads();

    // Per-lane channel plane base: img[b][l][*]
    const float* plane = img + ((size_t)b * CC + (size_t)l) * HWP;

    int rr[32];
    #pragma unroll
    for (int i = 0; i < 32; ++i) rr[i] = sRem[ci0 + i];   // wave-uniform

    float vv[32];
    #pragma unroll
    for (int i = 0; i < 32; ++i)
        vv[i] = (rr[i] >= 0) ? plane[rr[i]] : 0.0f;       // 32 loads in flight

    #pragma unroll
    for (int i = 0; i < 32; ++i) {
        int cell = ci0 + i;
        sT[(cell << 6) + (l ^ (cell & 31))] = vv[i];
    }
    __syncthreads();

    const int local = cell0 & (SS * SS - 1);
    float* op = out + (size_t)b * CC * (SS * SS) + local;
    #pragma unroll
    for (int j = 0; j < 16; ++j) {
        int c = w * 16 + j;
        float v0 = sT[((l)      << 6) + (c ^ (l & 31))];
        float v1 = sT[((l + 64) << 6) + (c ^ (l & 31))];
        float* oc = op + (size_t)c * (SS * SS);
        __builtin_nontemporal_store(v0, &oc[l]);      // 256 B coalesced
        __builtin_nontemporal_store(v1, &oc[64 + l]);
    }
}

extern "C" void kernel_launch(void* const* d_in, const int* in_sizes, int n_in,
                              void* d_out, int out_size, void* d_ws, size_t ws_size,
                              hipStream_t stream) {
    const float* img      = (const float*)d_in[0];
    const float* camera_k = (const float*)d_in[1];
    const float* depth    = (const float*)d_in[2];
    const float* mpp      = (const float*)d_in[3];

    unsigned long long* keys = (unsigned long long*)d_ws;

    // Empty-cell sentinel = 0xFFFF.. (no finite y maps to it).
    hipMemsetAsync(keys, 0xFF, (size_t)CELLS * sizeof(unsigned long long), stream);

    proj_kernel<<<BHW / 256, 256, 0, stream>>>(camera_k, depth, mpp, keys);
    scatter_kernel<<<CELLS / 128, 256, 0, stream>>>(img, keys, (float*)d_out);
}

// Round 5
// 812.521 us; speedup vs baseline: 1.0517x; 1.0304x over previous
//
#include <hip/hip_runtime.h>

// Problem constants (fixed by setup_inputs)
#define BB 8
#define CC 64
#define HH 128
#define WW 512
#define SS 512
#define HALF 256
#define HWP (HH * WW)        // 65536
#define BHW (BB * HWP)       // 524288
#define SSSS (SS * SS)       // 262144
#define CELLS (BB * SS * SS) // 2097152

__device__ __forceinline__ unsigned int order_f32(float f) {
    unsigned int u = __float_as_uint(f);
    return (u & 0x80000000u) ? ~u : (u | 0x80000000u);
}

// Kernel 1 (fused): per-block = 256 consecutive pixels of one batch.
//  (a) project each pixel, device-scope atomicMin packed (y, ~idx) key
//      into the single keys array (R0-proven path, ~155 us standalone).
//  (b) transpose this block's 256 pixels x 64 ch into img_t (B,HW,C);
//      the BW-bound transpose stream overlaps the latency-bound atomics
//      (R2 measured the fusion at ~213 us vs 241 separate).
__global__ __launch_bounds__(256) void proj_kernel(
    const float* __restrict__ img,
    const float* __restrict__ camera_k,
    const float* __restrict__ depth,
    const float* __restrict__ mpp_p,
    unsigned long long* __restrict__ keys,
    float* __restrict__ img_t)
{
    __shared__ float sk[9];
    __shared__ float tile[64][65];

    const int gp0 = blockIdx.x * 256;   // first global pixel (incl. batch)
    const int b   = gp0 >> 16;          // HW = 65536
    const int t   = threadIdx.x;
    const int idx = gp0 + t;

    if (t == 0) {
        const float rs[3] = {0.5f, 0.5f, 1.0f};
        double a[9];
        #pragma unroll
        for (int i = 0; i < 3; ++i)
            #pragma unroll
            for (int j = 0; j < 3; ++j)
                a[i*3 + j] = (double)__fmul_rn(camera_k[b*9 + i*3 + j], rs[i]);
        double det = a[0]*(a[4]*a[8]-a[5]*a[7])
                   - a[1]*(a[3]*a[8]-a[5]*a[6])
                   + a[2]*(a[3]*a[7]-a[4]*a[6]);
        double inv[9];
        inv[0] =  (a[4]*a[8]-a[5]*a[7])/det;
        inv[1] = -(a[1]*a[8]-a[2]*a[7])/det;
        inv[2] =  (a[1]*a[5]-a[2]*a[4])/det;
        inv[3] = -(a[3]*a[8]-a[5]*a[6])/det;
        inv[4] =  (a[0]*a[8]-a[2]*a[6])/det;
        inv[5] = -(a[0]*a[5]-a[2]*a[3])/det;
        inv[6] =  (a[3]*a[7]-a[4]*a[6])/det;
        inv[7] = -(a[0]*a[7]-a[1]*a[6])/det;
        inv[8] =  (a[0]*a[4]-a[1]*a[3])/det;
        #pragma unroll
        for (int i = 0; i < 9; ++i) sk[i] = (float)inv[i];
    }
    __syncthreads();

    // ---- (a) projection + atomic ----
    {
        const int rem = idx & (HWP - 1);
        const int v = rem >> 9;          // W = 512
        const int u = rem & (WW - 1);
        const float d = depth[idx];
        const float mpp = mpp_p[0];
        const float uf = (float)u, vf = (float)v;

        // Match numpy f32 semantics exactly: no FMA contraction.
        float xw = __fadd_rn(__fadd_rn(__fmul_rn(sk[0], uf), __fmul_rn(sk[1], vf)), sk[2]);
        float yw = __fadd_rn(__fadd_rn(__fmul_rn(sk[3], uf), __fmul_rn(sk[4], vf)), sk[5]);
        float zw = __fadd_rn(__fadd_rn(__fmul_rn(sk[6], uf), __fmul_rn(sk[7], vf)), sk[8]);
        float x3 = __fmul_rn(__fmul_rn(xw, d), 1.2f);
        float y3 = __fmul_rn(__fmul_rn(yw, d), 1.2f);
        float z3 = __fmul_rn(__fmul_rn(zw, d), 1.2f);

        int xi = (int)truncf(__fdiv_rn(x3, mpp));
        int zi = (int)truncf(__fdiv_rn(z3, mpp));

        if (xi >= -HALF && xi <= HALF - 1 && zi >= -HALF && zi <= HALF - 1) {
            int cell = (b << 18) | ((xi + HALF) << 9) | (zi + HALF);
            unsigned long long key =
                ((unsigned long long)order_f32(y3) << 32) | (unsigned int)(~idx);
            atomicMin(&keys[cell], key);
        }
    }

    // ---- (b) transpose 256 px x 64 ch, in 4 sub-tiles of 64 px ----
    const int lane = t & 63;
    const int grp  = t >> 6;             // 0..3
    const int p0   = gp0 & (HWP - 1);
    const float* src = img + (size_t)b * CC * HWP + p0;
    float*       dst = img_t + (size_t)gp0 * CC;

    #pragma unroll
    for (int s4 = 0; s4 < 4; ++s4) {
        __syncthreads();
        const float* ssrc = src + s4 * 64;
        #pragma unroll
        for (int i = 0; i < 16; ++i) {
            int ch = grp * 16 + i;
            tile[lane][ch] = ssrc[(size_t)ch * HWP + lane];
        }
        __syncthreads();
        float* sdst = dst + (size_t)(s4 * 64) * CC;
        #pragma unroll
        for (int i = 0; i < 16; ++i) {
            int p = grp * 16 + i;
            sdst[(size_t)p * CC + lane] = tile[p][lane];
        }
    }
}

// Kernel 2: scatter, NO LDS, no syncs.
// Block = 64 consecutive cells (one zz-run); wave = 16 cells.
// Lane l = (zc = l&15 cell-in-wave) | (csub = l>>4 channel slot).
//  keys: lanes 0-15 load the wave's 16 keys once; rem broadcast via shfl.
//  gather iter k (k=0..15): channel c = 4k+csub; per instruction the wave
//    reads 16 records x 16 B contiguous chunks of img_t (records are
//    256 B contiguous; their 2 lines are L1-reused across the 16 iters).
//    Fully-empty waves (the |z|>~70m band, >half the grid) skip gathers.
//  write iter k: out[b][c][xx][zz0+zc] -> 4 x 64 B contiguous segments
//    per instruction, non-temporal (keeps img_t resident in L2/L3).
__global__ __launch_bounds__(256) void scatter_kernel(
    const float* __restrict__ img_t,
    const unsigned long long* __restrict__ keys,
    float* __restrict__ out)
{
    const int cell0 = blockIdx.x * 64;
    const int b     = cell0 >> 18;
    const int t     = threadIdx.x;
    const int w     = t >> 6;           // wave 0..3
    const int l     = t & 63;
    const int zc    = l & 15;           // cell within wave
    const int csub  = l >> 4;           // channel slot 0..3
    const int cbase = cell0 + w * 16;   // wave's first cell

    int myrem = -1;
    if (l < 16) {
        unsigned long long k = keys[cbase + l];
        myrem = (k == ~0ull) ? -1
              : (int)((~(unsigned int)(k & 0xFFFFFFFFull)) & (HWP - 1));
    }
    const int rem = __shfl(myrem, zc);

    float v[16];
    if (__any(rem >= 0)) {
        const float* rec = img_t +
            (((size_t)b * HWP + (size_t)(rem >= 0 ? rem : 0)) << 6);
        #pragma unroll
        for (int k = 0; k < 16; ++k)
            v[k] = (rem >= 0) ? rec[4 * k + csub] : 0.0f;   // 16 loads in flight
    } else {
        #pragma unroll
        for (int k = 0; k < 16; ++k) v[k] = 0.0f;
    }

    const int localw = cbase & (SSSS - 1);      // xx*512 + zz0 (wave)
    float* op = out + (size_t)b * CC * SSSS + localw + zc;
    #pragma unroll
    for (int k = 0; k < 16; ++k) {
        int c = 4 * k + csub;
        __builtin_nontemporal_store(v[k], op + (size_t)c * SSSS);
    }
}

extern "C" void kernel_launch(void* const* d_in, const int* in_sizes, int n_in,
                              void* d_out, int out_size, void* d_ws, size_t ws_size,
                              hipStream_t stream) {
    const float* img      = (const float*)d_in[0];
    const float* camera_k = (const float*)d_in[1];
    const float* depth    = (const float*)d_in[2];
    const float* mpp      = (const float*)d_in[3];

    // ws layout: [0,16MiB) keys, [32MiB,160MiB) img_t
    unsigned long long* keys = (unsigned long long*)d_ws;
    float* img_t = (float*)((char*)d_ws + ((size_t)32 << 20));

    // Empty-cell sentinel = 0xFFFF.. (no finite y maps to it).
    hipMemsetAsync(keys, 0xFF, (size_t)CELLS * sizeof(unsigned long long), stream);

    proj_kernel<<<BHW / 256, 256, 0, stream>>>(img, camera_k, depth, mpp, keys, img_t);
    scatter_kernel<<<CELLS / 64, 256, 0, stream>>>(img_t, keys, (float*)d_out);
}